// Round 2
// baseline (115.504 us; speedup 1.0000x reference)
//
#include <hip/hip_runtime.h>
#include <math.h>

#define N_USERS 200000
#define N_ITEMS 200000
#define HOPS 4
#define DIM 64
#define BATCH 2048
#define N_NEGS 64
#define KK 2
#define ROW 256          // HOPS*DIM
#define DECAY 0.0001f

// ws layout: [0] ticket counter (uint, reset to 0 by hipMemsetAsync each call)
//            [16 .. 16+BATCH)        mf per batch element
//            [16+BATCH .. 16+2BATCH) reg per batch element
#define WS_OFF 16

// One block per batch element. 256 threads = 4 waves.
// Wave w scans candidates n = w, w+4, ..., for BOTH k-slices in one merged
// loop (two independent load streams -> deep MLP). Lane l covers row elements
// [4l,4l+3] (hop = l>>4). No LDS staging of user/pos rows: per-wave duplicate
// global loads are L1 hits and waves start gathering immediately.
__global__ __launch_bounds__(256, 4) void mixgcf_main(
    const float* __restrict__ user_emb,
    const float* __restrict__ item_emb,
    const float* __restrict__ seed_embed,
    const int*   __restrict__ user,
    const int*   __restrict__ pos_item,
    const int*   __restrict__ neg_item,
    float*       __restrict__ ws,
    float*       __restrict__ out)
{
    const int b    = blockIdx.x;
    const int tid  = threadIdx.x;
    const int w    = tid >> 6;     // wave id 0..3
    const int lane = tid & 63;

    __shared__ int   nidx[KK * N_NEGS];   // 128 candidate indices
    __shared__ float selv[KK][ROW];       // selected mixed rows
    __shared__ float scw[KK][4][HOPS];    // per-wave best score per hop
    __shared__ float red_mf[256];         // last-block reduction scratch
    __shared__ float red_rg[256];
    __shared__ int   last_flag;

    const int   uidx = user[b];
    const int   pidx = pos_item[b];
    const float seed = seed_embed[b];

    // Stage only the candidate indices (128 ints)
    if (tid < KK * N_NEGS) nidx[tid] = neg_item[(size_t)b * (KK * N_NEGS) + tid];
    __syncthreads();

    // Per-lane fragments, loaded directly (L1-duplicated across waves)
    const float4 s4 = *(const float4*)(user_emb + (size_t)uidx * ROW + lane * 4);
    const float4 p4 = *(const float4*)(item_emb + (size_t)pidx * ROW + lane * 4);
    const float  omse = 1.0f - seed;
    const float4 sp = make_float4(seed * p4.x, seed * p4.y, seed * p4.z, seed * p4.w);
    const int h = lane >> 4;   // hop this lane's 16-group owns

    float  best0 = -INFINITY, best1 = -INFINITY;
    float4 bv0 = make_float4(0.f, 0.f, 0.f, 0.f);
    float4 bv1 = make_float4(0.f, 0.f, 0.f, 0.f);

    #pragma unroll 8
    for (int i = 0; i < 16; ++i) {
        const int n   = (i << 2) + w;          // candidate within each k-slice
        const int it0 = nidx[n];               // wave-uniform broadcast reads
        const int it1 = nidx[N_NEGS + n];
        const float4 ne0 = *(const float4*)(item_emb + (size_t)it0 * ROW + lane * 4);
        const float4 ne1 = *(const float4*)(item_emb + (size_t)it1 * ROW + lane * 4);

        float4 m0, m1;
        m0.x = fmaf(omse, ne0.x, sp.x); m1.x = fmaf(omse, ne1.x, sp.x);
        m0.y = fmaf(omse, ne0.y, sp.y); m1.y = fmaf(omse, ne1.y, sp.y);
        m0.z = fmaf(omse, ne0.z, sp.z); m1.z = fmaf(omse, ne1.z, sp.z);
        m0.w = fmaf(omse, ne0.w, sp.w); m1.w = fmaf(omse, ne1.w, sp.w);

        float sc0 = m0.x * s4.x;  float sc1 = m1.x * s4.x;
        sc0 = fmaf(m0.y, s4.y, sc0); sc1 = fmaf(m1.y, s4.y, sc1);
        sc0 = fmaf(m0.z, s4.z, sc0); sc1 = fmaf(m1.z, s4.z, sc1);
        sc0 = fmaf(m0.w, s4.w, sc0); sc1 = fmaf(m1.w, s4.w, sc1);

        // reduce over the 16-lane hop group (two independent swizzle chains)
        sc0 += __shfl_xor(sc0, 1);  sc1 += __shfl_xor(sc1, 1);
        sc0 += __shfl_xor(sc0, 2);  sc1 += __shfl_xor(sc1, 2);
        sc0 += __shfl_xor(sc0, 4);  sc1 += __shfl_xor(sc1, 4);
        sc0 += __shfl_xor(sc0, 8);  sc1 += __shfl_xor(sc1, 8);

        // Ties only arise from duplicate item ids -> identical values.
        if (sc0 > best0) { best0 = sc0; bv0 = m0; }
        if (sc1 > best1) { best1 = sc1; bv1 = m1; }
    }

    // cross-wave argmax per (k, hop)
    if ((lane & 15) == 0) { scw[0][w][h] = best0; scw[1][w][h] = best1; }
    __syncthreads();
    {
        float a0 = scw[0][0][h], a1 = scw[0][1][h], a2 = scw[0][2][h], a3 = scw[0][3][h];
        int win0 = 0; float mb = a0;
        if (a1 > mb) { mb = a1; win0 = 1; }
        if (a2 > mb) { mb = a2; win0 = 2; }
        if (a3 > mb) { mb = a3; win0 = 3; }
        if (w == win0) *(float4*)(&selv[0][lane * 4]) = bv0;

        float c0 = scw[1][0][h], c1 = scw[1][1][h], c2 = scw[1][2][h], c3 = scw[1][3][h];
        int win1 = 0; float nb = c0;
        if (c1 > nb) { nb = c1; win1 = 1; }
        if (c2 > nb) { nb = c2; win1 = 2; }
        if (c3 > nb) { nb = c3; win1 = 3; }
        if (w == win1) *(float4*)(&selv[1][lane * 4]) = bv1;
    }
    __syncthreads();

    // Epilogue: wave 0, lane c = channel (user/pos rows are cache-hot)
    if (w == 0) {
        const int c = lane;
        const float* ur = user_emb + (size_t)uidx * ROW;
        const float* pr = item_emb + (size_t)pidx * ROW;
        const float ue = 0.25f * (ur[c] + ur[64 + c] + ur[128 + c] + ur[192 + c]);
        const float pe = 0.25f * (pr[c] + pr[64 + c] + pr[128 + c] + pr[192 + c]);
        const float n0 = 0.25f * (selv[0][c] + selv[0][64 + c] + selv[0][128 + c] + selv[0][192 + c]);
        const float n1 = 0.25f * (selv[1][c] + selv[1][64 + c] + selv[1][128 + c] + selv[1][192 + c]);
        float ps  = ue * pe;
        float ns0 = ue * n0;
        float ns1 = ue * n1;
        float rg  = ue * ue + pe * pe + n0 * n0 + n1 * n1;
        #pragma unroll
        for (int m = 1; m < 64; m <<= 1) {
            ps  += __shfl_xor(ps,  m);
            ns0 += __shfl_xor(ns0, m);
            ns1 += __shfl_xor(ns1, m);
            rg  += __shfl_xor(rg,  m);
        }
        if (lane == 0) {
            const float mf = log1pf(expf(ns0 - ps) + expf(ns1 - ps));
            ws[WS_OFF + b]         = mf;
            ws[WS_OFF + BATCH + b] = rg;
        }
    }

    // Last-block fused reduction (device-scope ticket; deterministic tree)
    if (tid == 0) {
        __threadfence();                       // release our ws writes
        unsigned t = atomicAdd((unsigned*)ws, 1u);
        last_flag = (t == (unsigned)(BATCH - 1));
    }
    __syncthreads();
    if (last_flag) {
        __threadfence();                       // acquire all blocks' ws writes
        float mf = 0.f, rg = 0.f;
        for (int i = tid; i < BATCH; i += 256) {
            mf += ws[WS_OFF + i];
            rg += ws[WS_OFF + BATCH + i];
        }
        red_mf[tid] = mf; red_rg[tid] = rg;
        __syncthreads();
        for (int s = 128; s > 0; s >>= 1) {
            if (tid < s) { red_mf[tid] += red_mf[tid + s]; red_rg[tid] += red_rg[tid + s]; }
            __syncthreads();
        }
        if (tid == 0) {
            const float mf_loss  = red_mf[0] / (float)BATCH;
            const float emb_loss = DECAY * (red_rg[0] * 0.5f) / (float)BATCH;
            out[0] = mf_loss + emb_loss;
            out[1] = mf_loss;
            out[2] = emb_loss;
        }
    }
}

extern "C" void kernel_launch(void* const* d_in, const int* in_sizes, int n_in,
                              void* d_out, int out_size, void* d_ws, size_t ws_size,
                              hipStream_t stream)
{
    const float* user_emb  = (const float*)d_in[0];
    const float* item_emb  = (const float*)d_in[1];
    const float* seed      = (const float*)d_in[2];
    const int*   user      = (const int*)d_in[3];
    const int*   pos_item  = (const int*)d_in[4];
    const int*   neg_item  = (const int*)d_in[5];
    float* ws  = (float*)d_ws;
    float* out = (float*)d_out;

    // Reset the ticket counter (graph-capturable async memset)
    hipMemsetAsync(d_ws, 0, 4, stream);
    mixgcf_main<<<BATCH, 256, 0, stream>>>(user_emb, item_emb, seed,
                                           user, pos_item, neg_item, ws, out);
}

// Round 3
// 50.426 us; speedup vs baseline: 2.2906x; 2.2906x over previous
//
#include <hip/hip_runtime.h>
#include <math.h>

#define N_USERS 200000
#define N_ITEMS 200000
#define HOPS 4
#define DIM 64
#define BATCH 2048
#define N_NEGS 64
#define KK 2
#define ROW 256          // HOPS*DIM
#define DECAY 0.0001f

// One block per batch element. 256 threads = 4 waves.
// Wave w scans candidates n = w, w+4, ..., for BOTH k-slices in one merged
// loop (two independent load streams). Lane l covers row elements [4l,4l+3]
// (hop = l>>4). No device-scope fences/atomics anywhere: the final reduction
// is a separate 1-block kernel (launch latency << fence serialization).
__global__ __launch_bounds__(256, 8) void mixgcf_main(
    const float* __restrict__ user_emb,
    const float* __restrict__ item_emb,
    const float* __restrict__ seed_embed,
    const int*   __restrict__ user,
    const int*   __restrict__ pos_item,
    const int*   __restrict__ neg_item,
    float*       __restrict__ ws)
{
    const int b    = blockIdx.x;
    const int tid  = threadIdx.x;
    const int w    = tid >> 6;     // wave id 0..3
    const int lane = tid & 63;

    __shared__ int   nidx[KK * N_NEGS];   // 128 candidate indices
    __shared__ float selv[KK][ROW];       // selected mixed rows
    __shared__ float scw[KK][4][HOPS];    // per-wave best score per hop

    const int   uidx = user[b];
    const int   pidx = pos_item[b];
    const float seed = seed_embed[b];

    // Stage only the candidate indices (128 ints)
    if (tid < KK * N_NEGS) nidx[tid] = neg_item[(size_t)b * (KK * N_NEGS) + tid];
    __syncthreads();

    // Per-lane fragments, loaded directly (duplicates across waves are L1 hits)
    const float4 s4 = *(const float4*)(user_emb + (size_t)uidx * ROW + lane * 4);
    const float4 p4 = *(const float4*)(item_emb + (size_t)pidx * ROW + lane * 4);
    const float  omse = 1.0f - seed;
    const float4 sp = make_float4(seed * p4.x, seed * p4.y, seed * p4.z, seed * p4.w);
    const int h = lane >> 4;   // hop this lane's 16-group owns

    float  best0 = -INFINITY, best1 = -INFINITY;
    float4 bv0 = make_float4(0.f, 0.f, 0.f, 0.f);
    float4 bv1 = make_float4(0.f, 0.f, 0.f, 0.f);

    #pragma unroll 8
    for (int i = 0; i < 16; ++i) {
        const int n   = (i << 2) + w;          // candidate within each k-slice
        const int it0 = nidx[n];               // wave-uniform broadcast reads
        const int it1 = nidx[N_NEGS + n];
        const float4 ne0 = *(const float4*)(item_emb + (size_t)it0 * ROW + lane * 4);
        const float4 ne1 = *(const float4*)(item_emb + (size_t)it1 * ROW + lane * 4);

        float4 m0, m1;
        m0.x = fmaf(omse, ne0.x, sp.x); m1.x = fmaf(omse, ne1.x, sp.x);
        m0.y = fmaf(omse, ne0.y, sp.y); m1.y = fmaf(omse, ne1.y, sp.y);
        m0.z = fmaf(omse, ne0.z, sp.z); m1.z = fmaf(omse, ne1.z, sp.z);
        m0.w = fmaf(omse, ne0.w, sp.w); m1.w = fmaf(omse, ne1.w, sp.w);

        float sc0 = m0.x * s4.x;  float sc1 = m1.x * s4.x;
        sc0 = fmaf(m0.y, s4.y, sc0); sc1 = fmaf(m1.y, s4.y, sc1);
        sc0 = fmaf(m0.z, s4.z, sc0); sc1 = fmaf(m1.z, s4.z, sc1);
        sc0 = fmaf(m0.w, s4.w, sc0); sc1 = fmaf(m1.w, s4.w, sc1);

        // reduce over the 16-lane hop group (two independent swizzle chains)
        sc0 += __shfl_xor(sc0, 1);  sc1 += __shfl_xor(sc1, 1);
        sc0 += __shfl_xor(sc0, 2);  sc1 += __shfl_xor(sc1, 2);
        sc0 += __shfl_xor(sc0, 4);  sc1 += __shfl_xor(sc1, 4);
        sc0 += __shfl_xor(sc0, 8);  sc1 += __shfl_xor(sc1, 8);

        // Ties only arise from duplicate item ids -> identical values.
        if (sc0 > best0) { best0 = sc0; bv0 = m0; }
        if (sc1 > best1) { best1 = sc1; bv1 = m1; }
    }

    // cross-wave argmax per (k, hop)
    if ((lane & 15) == 0) { scw[0][w][h] = best0; scw[1][w][h] = best1; }
    __syncthreads();
    {
        float a0 = scw[0][0][h], a1 = scw[0][1][h], a2 = scw[0][2][h], a3 = scw[0][3][h];
        int win0 = 0; float mb = a0;
        if (a1 > mb) { mb = a1; win0 = 1; }
        if (a2 > mb) { mb = a2; win0 = 2; }
        if (a3 > mb) { mb = a3; win0 = 3; }
        if (w == win0) *(float4*)(&selv[0][lane * 4]) = bv0;

        float c0 = scw[1][0][h], c1 = scw[1][1][h], c2 = scw[1][2][h], c3 = scw[1][3][h];
        int win1 = 0; float nb = c0;
        if (c1 > nb) { nb = c1; win1 = 1; }
        if (c2 > nb) { nb = c2; win1 = 2; }
        if (c3 > nb) { nb = c3; win1 = 3; }
        if (w == win1) *(float4*)(&selv[1][lane * 4]) = bv1;
    }
    __syncthreads();

    // Epilogue: wave 0, lane c = channel (user/pos rows are cache-hot)
    if (w == 0) {
        const int c = lane;
        const float* ur = user_emb + (size_t)uidx * ROW;
        const float* pr = item_emb + (size_t)pidx * ROW;
        const float ue = 0.25f * (ur[c] + ur[64 + c] + ur[128 + c] + ur[192 + c]);
        const float pe = 0.25f * (pr[c] + pr[64 + c] + pr[128 + c] + pr[192 + c]);
        const float n0 = 0.25f * (selv[0][c] + selv[0][64 + c] + selv[0][128 + c] + selv[0][192 + c]);
        const float n1 = 0.25f * (selv[1][c] + selv[1][64 + c] + selv[1][128 + c] + selv[1][192 + c]);
        float ps  = ue * pe;
        float ns0 = ue * n0;
        float ns1 = ue * n1;
        float rg  = ue * ue + pe * pe + n0 * n0 + n1 * n1;
        #pragma unroll
        for (int m = 1; m < 64; m <<= 1) {
            ps  += __shfl_xor(ps,  m);
            ns0 += __shfl_xor(ns0, m);
            ns1 += __shfl_xor(ns1, m);
            rg  += __shfl_xor(rg,  m);
        }
        if (lane == 0) {
            const float mf = log1pf(expf(ns0 - ps) + expf(ns1 - ps));
            ws[b]         = mf;
            ws[BATCH + b] = rg;
        }
    }
}

// Deterministic final reduction: one block, fixed tree.
__global__ __launch_bounds__(256) void mixgcf_reduce(const float* __restrict__ ws,
                                                     float* __restrict__ out)
{
    __shared__ float smf[256];
    __shared__ float srg[256];
    const int t = threadIdx.x;
    float mf = 0.f, rg = 0.f;
    #pragma unroll
    for (int i = 0; i < BATCH / 256; ++i) {
        mf += ws[t + i * 256];
        rg += ws[BATCH + t + i * 256];
    }
    smf[t] = mf; srg[t] = rg;
    __syncthreads();
    for (int s = 128; s > 0; s >>= 1) {
        if (t < s) { smf[t] += smf[t + s]; srg[t] += srg[t + s]; }
        __syncthreads();
    }
    if (t == 0) {
        const float mf_loss  = smf[0] / (float)BATCH;
        const float emb_loss = DECAY * (srg[0] * 0.5f) / (float)BATCH;
        out[0] = mf_loss + emb_loss;
        out[1] = mf_loss;
        out[2] = emb_loss;
    }
}

extern "C" void kernel_launch(void* const* d_in, const int* in_sizes, int n_in,
                              void* d_out, int out_size, void* d_ws, size_t ws_size,
                              hipStream_t stream)
{
    const float* user_emb  = (const float*)d_in[0];
    const float* item_emb  = (const float*)d_in[1];
    const float* seed      = (const float*)d_in[2];
    const int*   user      = (const int*)d_in[3];
    const int*   pos_item  = (const int*)d_in[4];
    const int*   neg_item  = (const int*)d_in[5];
    float* ws  = (float*)d_ws;
    float* out = (float*)d_out;

    mixgcf_main<<<BATCH, 256, 0, stream>>>(user_emb, item_emb, seed,
                                           user, pos_item, neg_item, ws);
    mixgcf_reduce<<<1, 256, 0, stream>>>(ws, out);
}